// Round 15
// baseline (1383.910 us; speedup 1.0000x reference)
//
#include <hip/hip_runtime.h>
#include <hip/hip_bf16.h>
#include <math.h>

#define NB    16
#define NPC   4096
#define MPC   1024
#define PTOT  65536
#define NCLU  16384
#define KNN_  16
#define CIN   64
#define COUT_ 128
#define CAUX_ 32

// out offsets (float elements)
#define OFF_XOUT   0
#define OFF_SUBPOS (NCLU*COUT_)
#define OFF_SUBB   (OFF_SUBPOS + NCLU*3)
#define OFF_AUX    (OFF_SUBB + NCLU)
#define OFF_IDCL   (OFF_AUX + NCLU*CAUX_)

// ws offsets (bytes)
#define WS_H        0
#define WS_CENTERS  (PTOT*COUT_*4)              // 33554432
#define WS_LISTS    (WS_CENTERS + NCLU*16)      // global top-16 key lists (2MB)
#define WS_STATS    (WS_LISTS + NCLU*KNN_*8)
#define WS_FLAGS    (WS_STATS + 1024)
// flag ints within WS_FLAGS:
#define FL_GEMM   0                              // completed GEMM tiles
#define FL_WORK   1                              // knn item queue
#define FL_GWORK  2                              // GEMM tile queue (work-stealing)
#define FL_PROG   3                              // 16 ints: FPS progress per cloud
#define FL_CNT    19                             // 512 ints: chunk list-initialized
#define FL_LOCK   531                            // 512 ints: chunk lock
#define FL_CHUNK  1043                           // 512 ints: slices done per chunk
#define FL_TOTAL  1555
#define WS_NEED_MEGA ((size_t)WS_FLAGS + 4u*FL_TOTAL)
#define WS_NEED_LEG  ((size_t)WS_STATS + 1024)

// ---- fps/gemm shared overlay (512 threads) ---------------------------------
#define SM_LX    0
#define SM_LY    16384
#define SM_LZ    32768
#define SM_CAND  49152
#define SM_CSEL  49664
#define SM_SIDX  53760
#define SM_HIST  70144
#define SM_SCANA 72192
#define SM_SCANB 74240
#define SM_SIZE  76288
// gemm view:
#define SM_XT    0
#define SM_WL    17408
#define SM_BS    50176
#define SM_BQ    50688
// knn view: cd overlays pos staging (sequential use)
#define KP_CD    0                               // 512*17*8 = 69632
#define KP_SCL   69632
#define KP_SSH   70144
#define KP_FID   70656                           // 512 ints
#define KP_FLAG  72704                           // 2 ints

__device__ __forceinline__ double dmax(double a, double b) { return __builtin_fmax(a, b); }
__device__ __forceinline__ double dmin(double a, double b) { return __builtin_fmin(a, b); }
__device__ __forceinline__ double pk(float d, int lo) {
  return __hiloint2double(__float_as_int(d), lo);
}
__device__ __forceinline__ int pk_lo(double k) {
  return (int)(unsigned)(__double_as_longlong(k) & 0xFFFFFFFFll);
}
template <int CTRL>
__device__ __forceinline__ double dpp64(double v) {
  long long u = __double_as_longlong(v);
  int lo = (int)(unsigned)(u & 0xFFFFFFFFll);
  int hi = (int)(unsigned)((unsigned long long)u >> 32);
  int rlo = __builtin_amdgcn_update_dpp(0, lo, CTRL, 0xf, 0xf, true);
  int rhi = __builtin_amdgcn_update_dpp(0, hi, CTRL, 0xf, 0xf, true);
  return __longlong_as_double(((long long)rhi << 32) | (long long)(unsigned)rlo);
}
template <int CTRL>
__device__ __forceinline__ float dpp32(float x) {
  return __int_as_float(__builtin_amdgcn_update_dpp(0, __float_as_int(x), CTRL, 0xf, 0xf, true));
}
#define ROR1 0x121
#define ROR2 0x122
#define ROR4 0x124
#define ROR8 0x128
__device__ __forceinline__ double rowmax16(double w) {
  w = dmax(w, dpp64<ROR1>(w)); w = dmax(w, dpp64<ROR2>(w));
  w = dmax(w, dpp64<ROR4>(w)); w = dmax(w, dpp64<ROR8>(w));
  return w;
}
__device__ __forceinline__ float row16maxf(float m) {
  m = fmaxf(m, dpp32<ROR1>(m)); m = fmaxf(m, dpp32<ROR2>(m));
  m = fmaxf(m, dpp32<ROR4>(m)); m = fmaxf(m, dpp32<ROR8>(m));
  return m;
}
__device__ __forceinline__ float row16minf(float m) {
  m = fminf(m, dpp32<ROR1>(m)); m = fminf(m, dpp32<ROR2>(m));
  m = fminf(m, dpp32<ROR4>(m)); m = fminf(m, dpp32<ROR8>(m));
  return m;
}
__device__ __forceinline__ int mort3(int x, int y, int z) {
  int m = 0;
  #pragma unroll
  for (int bb = 0; bb < 3; ++bb)
    m |= (((x >> bb) & 1) << (3*bb + 2)) | (((y >> bb) & 1) << (3*bb + 1)) |
         (((z >> bb) & 1) << (3*bb));
  return m;
}

// sorted-descending top-16 insert: L[0] = worst; 31 f64 min/max, no rescan
#define INS16(Lr, nk) do { \
  _Pragma("unroll") \
  for (int _m = 0; _m < 15; ++_m) Lr[_m] = dmin(Lr[_m], dmax(Lr[_m+1], (nk))); \
  Lr[15] = dmin(Lr[15], (nk)); } while (0)

#define KBIG __hiloint2double(0x7f7fffff, 0xffffffff)
#define CD_STRIDE 17

// ---------------- FPS (Morton sort + bbox prune + chunked flush) ------------
__device__ void fps_block(char* smem, const float* __restrict__ pos,
                          float4* __restrict__ centers, float* __restrict__ out,
                          int* prog)
{
  #pragma clang fp contract(off)
  float* lx = (float*)(smem + SM_LX);
  float* ly = (float*)(smem + SM_LY);
  float* lz = (float*)(smem + SM_LZ);
  double* cand = (double*)(smem + SM_CAND);
  int*   csel = (int*)(smem + SM_CSEL);
  int*   sidx = (int*)(smem + SM_SIDX);
  int*   hist = (int*)(smem + SM_HIST);
  float* bbs  = (float*)(smem + SM_HIST);
  int*   sA   = (int*)(smem + SM_SCANA);
  int*   sB   = (int*)(smem + SM_SCANB);
  const int b = blockIdx.x;
  const int t = threadIdx.x;
  const float* pb = pos + (size_t)b * NPC * 3;
  const int entry  = (t >> 6) * 4 + ((t >> 4) & 3);
  const bool writer = ((t & 15) == 0);

  float ox[8], oy[8], oz[8];
  {
    const float4* src = (const float4*)(pb + t * 24);
    float4 v[6];
    #pragma unroll
    for (int i = 0; i < 6; ++i) v[i] = src[i];
    const float* f = (const float*)v;
    #pragma unroll
    for (int j = 0; j < 8; ++j) {
      ox[j] = f[3*j]; oy[j] = f[3*j+1]; oz[j] = f[3*j+2];
      lx[t*8+j] = ox[j]; ly[t*8+j] = oy[j]; lz[t*8+j] = oz[j];
    }
  }
  float mnx = ox[0], mxx = ox[0], mny = oy[0], mxy = oy[0], mnz = oz[0], mxz = oz[0];
  #pragma unroll
  for (int j = 1; j < 8; ++j) {
    mnx = fminf(mnx, ox[j]); mxx = fmaxf(mxx, ox[j]);
    mny = fminf(mny, oy[j]); mxy = fmaxf(mxy, oy[j]);
    mnz = fminf(mnz, oz[j]); mxz = fmaxf(mxz, oz[j]);
  }
  mnx = row16minf(mnx); mxx = row16maxf(mxx);
  mny = row16minf(mny); mxy = row16maxf(mxy);
  mnz = row16minf(mnz); mxz = row16maxf(mxz);
  if (writer) {
    bbs[entry] = mnx; bbs[32+entry] = mxx; bbs[64+entry]  = mny;
    bbs[96+entry] = mxy; bbs[128+entry] = mnz; bbs[160+entry] = mxz;
  }
  __syncthreads();
  float gx0 = bbs[0], gx1 = bbs[32], gy0 = bbs[64], gy1 = bbs[96], gz0 = bbs[128], gz1 = bbs[160];
  #pragma unroll 8
  for (int w = 1; w < 32; ++w) {
    gx0 = fminf(gx0, bbs[w]);     gx1 = fmaxf(gx1, bbs[32+w]);
    gy0 = fminf(gy0, bbs[64+w]);  gy1 = fmaxf(gy1, bbs[96+w]);
    gz0 = fminf(gz0, bbs[128+w]); gz1 = fmaxf(gz1, bbs[160+w]);
  }
  __syncthreads();
  hist[t] = 0;
  __syncthreads();
  const float scx = 8.0f / ((gx1 - gx0) + 1e-6f);
  const float scy = 8.0f / ((gy1 - gy0) + 1e-6f);
  const float scz = 8.0f / ((gz1 - gz0) + 1e-6f);
  int key[8];
  #pragma unroll
  for (int j = 0; j < 8; ++j) {
    int cx = min(7, max(0, (int)((ox[j] - gx0) * scx)));
    int cy = min(7, max(0, (int)((oy[j] - gy0) * scy)));
    int cz = min(7, max(0, (int)((oz[j] - gz0) * scz)));
    key[j] = mort3(cx, cy, cz);
    atomicAdd(&hist[key[j]], 1);
  }
  __syncthreads();
  const int hv = hist[t];
  sA[t] = hv;
  __syncthreads();
  for (int off = 1; off < 512; off <<= 1) {
    const int o = (t >= off) ? sA[t - off] : 0;
    __syncthreads();
    sA[t] += o;
    __syncthreads();
  }
  sB[t] = sA[t] - hv;
  __syncthreads();
  #pragma unroll
  for (int j = 0; j < 8; ++j) {
    const int slot = atomicAdd(&sB[key[j]], 1);
    sidx[slot] = t*8 + j;
  }
  __syncthreads();
  float px[8], py[8], pz[8], mind[8];
  int lo8[8];
  float bxn = 1e30f, bxx = -1e30f, byn = 1e30f, byy = -1e30f, bzn = 1e30f, bzz = -1e30f;
  #pragma unroll
  for (int j = 0; j < 8; ++j) {
    const int sid = sidx[t*8 + j];
    px[j] = lx[sid]; py[j] = ly[sid]; pz[j] = lz[sid];
    lo8[j] = 4095 - sid;
    bxn = fminf(bxn, px[j]); bxx = fmaxf(bxx, px[j]);
    byn = fminf(byn, py[j]); byy = fmaxf(byy, py[j]);
    bzn = fminf(bzn, pz[j]); bzz = fmaxf(bzz, pz[j]);
  }
  const float x0 = lx[0], y0 = ly[0], z0 = lz[0];
  if (t == 0) csel[0] = 0;
  double bk;
  {
    double k4[4];
    #pragma unroll
    for (int jp = 0; jp < 4; ++jp) {
      const int j0 = 2*jp, j1 = 2*jp + 1;
      float dx0 = px[j0]-x0, dy0 = py[j0]-y0, dz0 = pz[j0]-z0;
      float dx1 = px[j1]-x0, dy1 = py[j1]-y0, dz1 = pz[j1]-z0;
      float d0 = (dx0*dx0 + dy0*dy0) + dz0*dz0;   // no-FMA
      float d1 = (dx1*dx1 + dy1*dy1) + dz1*dz1;
      mind[j0] = d0; mind[j1] = d1;
      k4[jp] = dmax(pk(d0, lo8[j0]), pk(d1, lo8[j1]));
    }
    bk = dmax(dmax(k4[0], k4[1]), dmax(k4[2], k4[3]));
  }

  for (int s = 1; s < MPC; ++s) {
    double w = rowmax16(bk);
    const int ph = (s & 1) * 32;
    if (writer) cand[ph + entry] = w;
    __syncthreads();
    if ((s & 31) == 0) {                 // flush chunk [s-32, s)
      if (t < 32) {
        const int fc = s - 32 + t;
        const int il = csel[fc];
        const int cl = b*MPC + fc;
        const float X = lx[il], Y = ly[il], Z = lz[il];
        centers[cl] = make_float4(X, Y, Z, 0.0f);
        out[OFF_SUBPOS + cl*3 + 0] = X;
        out[OFF_SUBPOS + cl*3 + 1] = Y;
        out[OFF_SUBPOS + cl*3 + 2] = Z;
        out[OFF_SUBB + cl] = (float)b;
        out[OFF_IDCL + cl] = (float)(b*NPC + il);
      }
      __syncthreads();
      if (prog && t == 0) { __threadfence(); atomicExch(&prog[b], s); }
    }
    double2 pr = ((const double2*)(cand + ph))[t & 15];
    double w2 = rowmax16(dmax(pr.x, pr.y));
    const int sel = 4095 - pk_lo(w2);
    const float sx = lx[sel], sy = ly[sel], sz = lz[sel];
    if (t == 0) csel[s] = sel;
    const float bkhi = __int_as_float(__double2hiint(bk));
    const float cxd = fmaxf(fmaxf(bxn - sx, sx - bxx), 0.0f);
    const float cyd = fmaxf(fmaxf(byn - sy, sy - byy), 0.0f);
    const float czd = fmaxf(fmaxf(bzn - sz, sz - bzz), 0.0f);
    const float lb = 0.99f * ((cxd*cxd + cyd*cyd) + czd*czd);
    if (lb < bkhi) {
      double k4[4];
      #pragma unroll
      for (int jp = 0; jp < 4; ++jp) {
        const int j0 = 2*jp, j1 = 2*jp + 1;
        float dx0 = px[j0]-sx, dy0 = py[j0]-sy, dz0 = pz[j0]-sz;
        float dx1 = px[j1]-sx, dy1 = py[j1]-sy, dz1 = pz[j1]-sz;
        float d0 = (dx0*dx0 + dy0*dy0) + dz0*dz0;
        float d1 = (dx1*dx1 + dy1*dy1) + dz1*dz1;
        float m0 = fminf(mind[j0], d0), m1 = fminf(mind[j1], d1);
        mind[j0] = m0; mind[j1] = m1;
        k4[jp] = dmax(pk(m0, lo8[j0]), pk(m1, lo8[j1]));
      }
      bk = dmax(dmax(k4[0], k4[1]), dmax(k4[2], k4[3]));
    }
  }
  __syncthreads();
  if (t < 32) {
    const int fc = 992 + t;
    const int il = csel[fc];
    const int cl = b*MPC + fc;
    const float X = lx[il], Y = ly[il], Z = lz[il];
    centers[cl] = make_float4(X, Y, Z, 0.0f);
    out[OFF_SUBPOS + cl*3 + 0] = X;
    out[OFF_SUBPOS + cl*3 + 1] = Y;
    out[OFF_SUBPOS + cl*3 + 2] = Z;
    out[OFF_SUBB + cl] = (float)b;
    out[OFF_IDCL + cl] = (float)(b*NPC + il);
  }
  __syncthreads();
  if (prog && t == 0) { __threadfence(); atomicExch(&prog[b], MPC); }
}

// ---------------- GEMM tile (512 thr) ---------------------------------------
__device__ void gemm_tile(char* smem, const float* __restrict__ x,
                          const float* __restrict__ W, const float* __restrict__ bias,
                          float* __restrict__ h, float* __restrict__ stats, int blk)
{
  float (*xT)[68]  = (float(*)[68])(smem + SM_XT);
  float (*Wl)[128] = (float(*)[128])(smem + SM_WL);
  float* bsum = (float*)(smem + SM_BS);
  float* bsq  = (float*)(smem + SM_BQ);
  const int t = threadIdx.x;
  const int row0 = blk * 64;
  if (t < 128) { bsum[t] = 0.0f; bsq[t] = 0.0f; }
  #pragma unroll
  for (int i = 0; i < 8; ++i) {
    const int idx = t + i*512;
    xT[idx & 63][idx >> 6] = x[(size_t)row0*64 + idx];
  }
  #pragma unroll
  for (int i = 0; i < 16; ++i) {
    const int idx = t + i*512;
    ((float*)Wl)[idx] = W[idx];
  }
  __syncthreads();
  const int tx = t & 31, ty = t >> 5;
  float acc[4][4] = {};
  #pragma unroll 8
  for (int k = 0; k < 64; ++k) {
    const float4 a  = *(const float4*)&xT[k][ty*4];
    const float4 b0 = *(const float4*)&Wl[k][tx*4];
    const float av[4] = {a.x, a.y, a.z, a.w};
    const float bw[4] = {b0.x, b0.y, b0.z, b0.w};
    #pragma unroll
    for (int i2 = 0; i2 < 4; ++i2)
      #pragma unroll
      for (int e = 0; e < 4; ++e)
        acc[i2][e] += av[i2] * bw[e];
  }
  const int c0 = tx*4;
  float bb[4];
  #pragma unroll
  for (int e = 0; e < 4; ++e) bb[e] = bias[c0+e];
  float s4[4] = {}, q4[4] = {};
  #pragma unroll
  for (int i2 = 0; i2 < 4; ++i2) {
    float vv[4];
    #pragma unroll
    for (int e = 0; e < 4; ++e) {
      float v = acc[i2][e] + bb[e];
      vv[e] = v; s4[e] += v; q4[e] += v*v;
    }
    const int r = row0 + ty*4 + i2;
    *(float4*)&h[(size_t)r*128 + c0] = make_float4(vv[0], vv[1], vv[2], vv[3]);
  }
  #pragma unroll
  for (int e = 0; e < 4; ++e) {
    atomicAdd(&bsum[c0+e], s4[e]);
    atomicAdd(&bsq[c0+e],  q4[e]);
  }
  __syncthreads();
  if (t < 128) {
    atomicAdd(&stats[t],      bsum[t]);
    atomicAdd(&stats[128+t],  bsq[t]);
  }
  __syncthreads();
}

// ---------------- MEGA: FPS + GEMM (work-stealing) + pipelined kNN/pool -----
__global__ __launch_bounds__(512, 4)
void mega2(const float* __restrict__ pos, float4* __restrict__ centers,
           float* __restrict__ out, const float* __restrict__ x,
           const float* __restrict__ W, const float* __restrict__ bias,
           float* __restrict__ h, float* __restrict__ stats,
           double* __restrict__ lists, int* __restrict__ flags,
           const float* __restrict__ gamma, const float* __restrict__ beta,
           const float* __restrict__ aux)
{
  #pragma clang fp contract(off)
  __shared__ __align__(16) char smem[SM_SIZE];
  const int t = threadIdx.x;
  int* sfl = (int*)(smem + KP_FLAG);     // [0]=item, [1]=aux flag
  if (blockIdx.x < NB) {
    fps_block(smem, pos, centers, out, flags + FL_PROG);
    return;
  }
  // ---- GEMM phase: work-stealing over 1024 row-tiles (residency-robust) ----
  for (;;) {
    __syncthreads();
    if (t == 0) sfl[0] = atomicAdd(&flags[FL_GWORK], 1);
    __syncthreads();
    const int gid = sfl[0];
    if (gid >= 1024) break;
    gemm_tile(smem, x, W, bias, h, stats, gid);
    if (t == 0) { __threadfence(); atomicAdd(&flags[FL_GEMM], 1); }
  }
  // ---- consumer phase: pull (chunk, slice) items ----
  double* cd  = (double*)(smem + KP_CD);
  float*  scl = (float*)(smem + KP_SCL);
  float*  ssh = (float*)(smem + KP_SSH);
  int*    fid = (int*)(smem + KP_FID);
  const int q  = t & 15;
  const int cc = t >> 4;                 // 0..31
  for (;;) {
    __syncthreads();
    if (t == 0) sfl[0] = atomicAdd(&flags[FL_WORK], 1);
    __syncthreads();
    const int id = sfl[0];
    if (id >= 2048) break;
    const int slice   = id & 3;
    const int chunkid = id >> 2;         // 0..511
    const int cloud   = chunkid & 15;
    const int cidx    = chunkid >> 4;    // 0..31
    const int c0      = cidx * 32;
    if (t == 0) {
      while (atomicAdd(&flags[FL_PROG + cloud], 0) < c0 + 32)
        __builtin_amdgcn_s_sleep(32);
    }
    __syncthreads();
    __threadfence();                     // acquire: fresh centers
    float4* mpos = (float4*)smem;        // stage this slice's 1024 points
    {
      const float* pb = pos + ((size_t)cloud * NPC + slice * 1024) * 3;
      for (int i = t; i < 1024; i += 512)
        mpos[i] = make_float4(pb[3*i], pb[3*i+1], pb[3*i+2], 0.0f);
    }
    __syncthreads();
    const float4 C = centers[cloud*MPC + c0 + cc];
    double L[16];
    #pragma unroll
    for (int k = 0; k < 16; ++k) L[k] = KBIG;
    for (int jj = 0; jj < 64; ++jj) {
      const int jl = jj*16 + q;
      const float4 p = mpos[jl];
      float dx = C.x - p.x, dy = C.y - p.y, dz = C.z - p.z;
      float d2 = (dx*dx + dy*dy) + dz*dz;  // no-FMA
      double nk = pk(d2, slice*1024 + jl);
      if (nk < L[0]) INS16(L, nk);
    }
    __syncthreads();                     // pos dead; cd overlays
    #pragma unroll
    for (int k = 0; k < 16; ++k) cd[t*CD_STRIDE + k] = L[k];
    __syncthreads();
    if (q < 4) {                         // merge 16 -> 4
      #pragma unroll
      for (int r = 1; r <= 3; ++r) {
        const double* src = cd + (cc*16 + q + 4*r)*CD_STRIDE;
        #pragma unroll
        for (int k = 0; k < 16; ++k) {
          double nk = src[k];
          if (nk < L[0]) INS16(L, nk);
        }
      }
      #pragma unroll
      for (int k = 0; k < 16; ++k) cd[t*CD_STRIDE + k] = L[k];
    }
    __syncthreads();
    if (q == 0) {                        // merge 4 -> 1 (slice-local top-16)
      #pragma unroll
      for (int r = 1; r <= 3; ++r) {
        const double* src = cd + (cc*16 + r)*CD_STRIDE;
        #pragma unroll
        for (int k = 0; k < 16; ++k) {
          double nk = src[k];
          if (nk < L[0]) INS16(L, nk);
        }
      }
    }
    // ---- SINGLE per-chunk lock (t0 only -> no multi-lock deadlock) --------
    if (t == 0) {
      while (atomicCAS(&flags[FL_LOCK + chunkid], 0, 1) != 0)
        __builtin_amdgcn_s_sleep(8);
    }
    __syncthreads();                     // lock held for whole block
    __threadfence();                     // acquire lists
    if (q == 0) {
      double* gl = lists + (size_t)(cloud*MPC + c0 + cc) * 16;
      if (atomicAdd(&flags[FL_CNT + chunkid], 0) != 0) {
        #pragma unroll
        for (int k = 0; k < 16; ++k) {
          double nk = gl[k];
          if (nk < L[0]) INS16(L, nk);
        }
      }
      #pragma unroll
      for (int k = 0; k < 16; ++k) gl[k] = L[k];
    }
    __threadfence();                     // release lists
    __syncthreads();
    if (t == 0) {
      atomicExch(&flags[FL_CNT + chunkid], 1);
      __threadfence();
      atomicExch(&flags[FL_LOCK + chunkid], 0);
      const int dn = atomicAdd(&flags[FL_CHUNK + chunkid], 1);
      sfl[1] = (dn == 3) ? 1 : 0;
    }
    __syncthreads();
    if (sfl[1]) {                        // last slice of chunk: pool it
      if (t == 0) {
        while (atomicAdd(&flags[FL_GEMM], 0) < 1024)
          __builtin_amdgcn_s_sleep(32);
      }
      __syncthreads();
      __threadfence();                   // acquire h/stats/lists
      if (t < 128) {
        const float inv = 1.0f / 65536.0f;
        const float mu  = stats[t] * inv;
        const float var = stats[128+t] * inv - mu*mu;
        const float sc  = gamma[t] * rsqrtf(var + 1e-5f);
        scl[t] = sc;
        ssh[t] = beta[t] - mu*sc;
      }
      {
        const int g = cloud*MPC + c0 + (t >> 4);
        fid[t] = cloud*NPC + pk_lo(lists[(size_t)g*16 + (t & 15)]);
      }
      __syncthreads();
      for (int g2 = 0; g2 < 8; ++g2) {
        const int cc2 = g2*4 + (t >> 7);
        const int col = t & 127;
        const int cl  = cloud*MPC + c0 + cc2;
        const float sc = scl[col], sh = ssh[col];
        float mv = 0.0f;
        #pragma unroll
        for (int k = 0; k < 16; ++k) {
          const float hv = h[(size_t)fid[cc2*16 + k]*128 + col];
          mv = fmaxf(mv, fmaxf(sc*hv + sh, 0.0f));
        }
        out[OFF_XOUT + (size_t)cl*128 + col] = mv;
        if (col < 32) {
          float s = 0.0f;
          #pragma unroll
          for (int k = 0; k < 16; ++k) s += aux[(size_t)fid[cc2*16 + k]*32 + col];
          out[OFF_AUX + (size_t)cl*32 + col] = s * (1.0f/16.0f);
        }
      }
    }
  }
}

// ---- legacy path (R12): fused fps/gemm kernel + knn_pool kernel ------------
__global__ __launch_bounds__(512) void fused_fps_gemm(const float* __restrict__ pos,
                                                      float4* __restrict__ centers,
                                                      float* __restrict__ out,
                                                      const float* __restrict__ x,
                                                      const float* __restrict__ W,
                                                      const float* __restrict__ bias,
                                                      float* __restrict__ h,
                                                      float* __restrict__ stats)
{
  __shared__ __align__(16) char smem[SM_SIZE];
  if (blockIdx.x < NB) fps_block(smem, pos, centers, out, nullptr);
  else                 gemm_tile(smem, x, W, bias, h, stats, blockIdx.x - NB);
}

__global__ __launch_bounds__(512) void knn_pool(const float* __restrict__ pos,
                                                const float4* __restrict__ centers,
                                                const float* __restrict__ h,
                                                const float* __restrict__ aux,
                                                const float* __restrict__ stats,
                                                const float* __restrict__ gamma,
                                                const float* __restrict__ beta,
                                                float* __restrict__ out)
{
  #pragma clang fp contract(off)
  __shared__ __align__(16) char sm2[76288];
  float4* lp = (float4*)(sm2);
  double* cd = (double*)(sm2 + KP_CD);
  float*  scl = (float*)(sm2 + KP_SCL);
  float*  ssh = (float*)(sm2 + KP_SSH);
  int*    fid = (int*)(sm2 + KP_FID);
  const int vblk = ((blockIdx.x & 7) << 6) | (blockIdx.x >> 3);
  const int b   = vblk >> 5;
  const int c0  = (vblk & 31) * 32;
  const int t   = threadIdx.x;
  const int q   = t & 15;
  const int cc  = t >> 4;
  if (t < 128) {
    const float inv = 1.0f / 65536.0f;
    const float mu  = stats[t] * inv;
    const float var = stats[128+t] * inv - mu*mu;
    const float sc  = gamma[t] * rsqrtf(var + 1e-5f);
    scl[t] = sc;
    ssh[t] = beta[t] - mu*sc;
  }
  const float* pb = pos + (size_t)b * NPC * 3;
  for (int i = t; i < NPC; i += 512)
    lp[i] = make_float4(pb[3*i], pb[3*i+1], pb[3*i+2], 0.0f);
  __syncthreads();
  const float4 C = centers[b*MPC + c0 + cc];
  double L[16];
  #pragma unroll
  for (int k = 0; k < 16; ++k) L[k] = KBIG;
  for (int jj = 0; jj < NPC/16; ++jj) {
    const int j = jj*16 + q;
    const float4 p = lp[j];
    float dx = C.x - p.x, dy = C.y - p.y, dz = C.z - p.z;
    float d2 = (dx*dx + dy*dy) + dz*dz;
    double nk = pk(d2, j);
    if (nk < L[0]) INS16(L, nk);
  }
  __syncthreads();
  #pragma unroll
  for (int k = 0; k < 16; ++k) cd[t*CD_STRIDE + k] = L[k];
  __syncthreads();
  if (q < 4) {
    #pragma unroll
    for (int r = 1; r <= 3; ++r) {
      const double* src = cd + (cc*16 + q + 4*r)*CD_STRIDE;
      #pragma unroll
      for (int k = 0; k < 16; ++k) {
        double nk = src[k];
        if (nk < L[0]) INS16(L, nk);
      }
    }
    #pragma unroll
    for (int k = 0; k < 16; ++k) cd[t*CD_STRIDE + k] = L[k];
  }
  __syncthreads();
  if (q == 0) {
    #pragma unroll
    for (int r = 1; r <= 3; ++r) {
      const double* src = cd + (cc*16 + r)*CD_STRIDE;
      #pragma unroll
      for (int k = 0; k < 16; ++k) {
        double nk = src[k];
        if (nk < L[0]) INS16(L, nk);
      }
    }
    #pragma unroll
    for (int k = 0; k < 16; ++k) fid[cc*16 + k] = b*NPC + pk_lo(L[k]);
  }
  __syncthreads();
  for (int g = 0; g < 8; ++g) {
    const int cc2 = g*4 + (t >> 7);
    const int col = t & 127;
    const int cl  = b*MPC + c0 + cc2;
    const float sc = scl[col], sh = ssh[col];
    float mv = 0.0f;
    #pragma unroll
    for (int k = 0; k < 16; ++k) {
      const float hv = h[(size_t)fid[cc2*16 + k]*128 + col];
      mv = fmaxf(mv, fmaxf(sc*hv + sh, 0.0f));
    }
    out[OFF_XOUT + (size_t)cl*128 + col] = mv;
    if (col < 32) {
      float s = 0.0f;
      #pragma unroll
      for (int k = 0; k < 16; ++k) s += aux[(size_t)fid[cc2*16 + k]*32 + col];
      out[OFF_AUX + (size_t)cl*32 + col] = s * (1.0f/16.0f);
    }
  }
}

extern "C" void kernel_launch(void* const* d_in, const int* in_sizes, int n_in,
                              void* d_out, int out_size, void* d_ws, size_t ws_size,
                              hipStream_t stream)
{
  const float* x     = (const float*)d_in[0];
  const float* pos   = (const float*)d_in[1];
  const float* aux   = (const float*)d_in[3];
  const float* W     = (const float*)d_in[4];
  const float* bias  = (const float*)d_in[5];
  const float* gamma = (const float*)d_in[6];
  const float* beta  = (const float*)d_in[7];
  float* out = (float*)d_out;
  char*  ws  = (char*)d_ws;
  if (ws_size < WS_NEED_LEG) return;

  float*  h       = (float*)(ws + WS_H);
  float4* centers = (float4*)(ws + WS_CENTERS);
  double* lists   = (double*)(ws + WS_LISTS);
  float*  stats   = (float*)(ws + WS_STATS);
  int*    flags   = (int*)(ws + WS_FLAGS);

  if (ws_size >= WS_NEED_MEGA) {
    hipMemsetAsync(stats, 0, 1024 + 4*FL_TOTAL, stream);
    hipLaunchKernelGGL(mega2, dim3(512), dim3(512), 0, stream,
                       pos, centers, out, x, W, bias, h, stats,
                       lists, flags, gamma, beta, aux);
  } else {
    hipMemsetAsync(stats, 0, 1024, stream);
    hipLaunchKernelGGL(fused_fps_gemm, dim3(NB + PTOT/64), dim3(512), 0, stream,
                       pos, centers, out, x, W, bias, h, stats);
    hipLaunchKernelGGL(knn_pool, dim3(512), dim3(512), 0, stream,
                       pos, centers, h, aux, stats, gamma, beta, out);
  }
}

// Round 16
// 735.233 us; speedup vs baseline: 1.8823x; 1.8823x over previous
//
#include <hip/hip_runtime.h>
#include <hip/hip_bf16.h>
#include <math.h>

#define NB    16
#define NPC   4096        // points per cloud
#define MPC   1024        // clusters per cloud
#define PTOT  65536
#define NCLU  16384
#define KNN_  16
#define CIN   64
#define COUT_ 128
#define CAUX_ 32

// out offsets (float elements), outputs concatenated in reference return order
#define OFF_XOUT   0
#define OFF_SUBPOS (NCLU*COUT_)               // 2097152
#define OFF_SUBB   (OFF_SUBPOS + NCLU*3)      // 2146304
#define OFF_AUX    (OFF_SUBB + NCLU)          // 2162688
#define OFF_IDCL   (OFF_AUX + NCLU*CAUX_)     // 2686976

// ws offsets (bytes)
#define WS_H        0
#define WS_CENTERS  (PTOT*COUT_*4)            // h: P x 128 f32
#define WS_STATS    (WS_CENTERS + NCLU*16)    // centers: float4 per cluster
#define WS_NEED     (WS_STATS + 256*4)

// ---- shared-memory overlay for the fused fps/gemm kernel (512 threads) -----
#define SM_LX    0                      // 4096 f  (16384 B)
#define SM_LY    16384
#define SM_LZ    32768
#define SM_CAND  49152                  // 2 * 32 f64 = 512 B
#define SM_CSEL  49664                  // 1024 int = 4096 B -> 53760
#define SM_SIDX  53760                  // 4096 int = 16384 B -> 70144
#define SM_HIST  70144                  // 512 int = 2048 B (bbox scratch overlays)
#define SM_SCANA 72192                  // 512 int
#define SM_SCANB 74240                  // 512 int -> 76288
// gemm view:
#define SM_XT    0                      // float[64][68] = 17408 B
#define SM_WL    17408                  // float[64][128] = 32768 B -> 50176
#define SM_BS    50176                  // float[128]
#define SM_BQ    50688                  // float[128] -> 51200
#define SM_SIZE  76288

// f64-packed keys: hi32 = f32 bits of d2 (>=0, finite -> positive f64, no NaN),
// lo32 = index payload. Positive doubles order exactly as their u64 bit
// patterns; f64 denormals are never flushed on AMD -> v_max_f64/v_min_f64 is a
// single-instruction lexicographic compare.
__device__ __forceinline__ double dmax(double a, double b) { return __builtin_fmax(a, b); }
__device__ __forceinline__ double dmin(double a, double b) { return __builtin_fmin(a, b); }
__device__ __forceinline__ double pk(float d, int lo) {
  return __hiloint2double(__float_as_int(d), lo);
}
__device__ __forceinline__ int pk_lo(double k) {
  return (int)(unsigned)(__double_as_longlong(k) & 0xFFFFFFFFll);
}

// DPP row_ror:N (rotate within 16-lane row; all source lanes valid).
template <int CTRL>
__device__ __forceinline__ double dpp64(double v) {
  long long u = __double_as_longlong(v);
  int lo = (int)(unsigned)(u & 0xFFFFFFFFll);
  int hi = (int)(unsigned)((unsigned long long)u >> 32);
  int rlo = __builtin_amdgcn_update_dpp(0, lo, CTRL, 0xf, 0xf, true);
  int rhi = __builtin_amdgcn_update_dpp(0, hi, CTRL, 0xf, 0xf, true);
  return __longlong_as_double(((long long)rhi << 32) | (long long)(unsigned)rlo);
}
template <int CTRL>
__device__ __forceinline__ float dpp32(float x) {
  return __int_as_float(__builtin_amdgcn_update_dpp(0, __float_as_int(x), CTRL, 0xf, 0xf, true));
}
#define ROR1 0x121
#define ROR2 0x122
#define ROR4 0x124
#define ROR8 0x128

__device__ __forceinline__ double rowmax16(double w) {
  w = dmax(w, dpp64<ROR1>(w));
  w = dmax(w, dpp64<ROR2>(w));
  w = dmax(w, dpp64<ROR4>(w));
  w = dmax(w, dpp64<ROR8>(w));
  return w;
}
__device__ __forceinline__ float row16maxf(float m) {
  m = fmaxf(m, dpp32<ROR1>(m));
  m = fmaxf(m, dpp32<ROR2>(m));
  m = fmaxf(m, dpp32<ROR4>(m));
  m = fmaxf(m, dpp32<ROR8>(m));
  return m;
}
__device__ __forceinline__ float row16minf(float m) {
  m = fminf(m, dpp32<ROR1>(m));
  m = fminf(m, dpp32<ROR2>(m));
  m = fminf(m, dpp32<ROR4>(m));
  m = fminf(m, dpp32<ROR8>(m));
  return m;
}

// 9-bit Morton code from 3x3-bit cell coords
__device__ __forceinline__ int mort3(int x, int y, int z) {
  int m = 0;
  #pragma unroll
  for (int bb = 0; bb < 3; ++bb)
    m |= (((x >> bb) & 1) << (3*bb + 2)) | (((y >> bb) & 1) << (3*bb + 1)) |
         (((z >> bb) & 1) << (3*bb));
  return m;
}

// ---------------- FPS block: Morton-sorted ownership + bbox pruning ---------
// Ownership is output-invariant: a group update is skipped only when it is
// PROVEN that fminf(mind,d)==mind for every owned point, so each point's mind
// trajectory (and hence the argmax sequence) is identical to the unpruned run.
__device__ void fps_block(char* smem, const float* __restrict__ pos,
                          float4* __restrict__ centers, float* __restrict__ out)
{
  #pragma clang fp contract(off)
  float* lx = (float*)(smem + SM_LX);
  float* ly = (float*)(smem + SM_LY);
  float* lz = (float*)(smem + SM_LZ);
  double* cand = (double*)(smem + SM_CAND);
  int*   csel = (int*)(smem + SM_CSEL);
  int*   sidx = (int*)(smem + SM_SIDX);
  int*   hist = (int*)(smem + SM_HIST);
  float* bbs  = (float*)(smem + SM_HIST);   // bbox scratch overlays hist
  int*   sA   = (int*)(smem + SM_SCANA);
  int*   sB   = (int*)(smem + SM_SCANB);
  const int b = blockIdx.x;
  const int t = threadIdx.x;
  const float* pb = pos + (size_t)b * NPC * 3;
  const int entry  = (t >> 6) * 4 + ((t >> 4) & 3);   // wid*4 + row = 0..31
  const bool writer = ((t & 15) == 0);                // lane 0 of each row

  // ---- load 8 consecutive original points; fill LDS coords -----------------
  float ox[8], oy[8], oz[8];
  {
    const float4* src = (const float4*)(pb + t * 24);
    float4 v[6];
    #pragma unroll
    for (int i = 0; i < 6; ++i) v[i] = src[i];
    const float* f = (const float*)v;
    #pragma unroll
    for (int j = 0; j < 8; ++j) {
      ox[j] = f[3*j]; oy[j] = f[3*j+1]; oz[j] = f[3*j+2];
      lx[t*8+j] = ox[j]; ly[t*8+j] = oy[j]; lz[t*8+j] = oz[j];
    }
  }
  // ---- cloud bbox (performance-only; any value is correct) -----------------
  float mnx = ox[0], mxx = ox[0], mny = oy[0], mxy = oy[0], mnz = oz[0], mxz = oz[0];
  #pragma unroll
  for (int j = 1; j < 8; ++j) {
    mnx = fminf(mnx, ox[j]); mxx = fmaxf(mxx, ox[j]);
    mny = fminf(mny, oy[j]); mxy = fmaxf(mxy, oy[j]);
    mnz = fminf(mnz, oz[j]); mxz = fmaxf(mxz, oz[j]);
  }
  mnx = row16minf(mnx); mxx = row16maxf(mxx);
  mny = row16minf(mny); mxy = row16maxf(mxy);
  mnz = row16minf(mnz); mxz = row16maxf(mxz);
  if (writer) {
    bbs[entry] = mnx; bbs[32+entry] = mxx; bbs[64+entry]  = mny;
    bbs[96+entry] = mxy; bbs[128+entry] = mnz; bbs[160+entry] = mxz;
  }
  __syncthreads();
  float gx0 = bbs[0], gx1 = bbs[32], gy0 = bbs[64], gy1 = bbs[96], gz0 = bbs[128], gz1 = bbs[160];
  #pragma unroll 8
  for (int w = 1; w < 32; ++w) {
    gx0 = fminf(gx0, bbs[w]);     gx1 = fmaxf(gx1, bbs[32+w]);
    gy0 = fminf(gy0, bbs[64+w]);  gy1 = fmaxf(gy1, bbs[96+w]);
    gz0 = fminf(gz0, bbs[128+w]); gz1 = fmaxf(gz1, bbs[160+w]);
  }
  __syncthreads();                       // bbox reads done before hist zeroing
  hist[t] = 0;
  __syncthreads();
  // ---- Morton keys + histogram ---------------------------------------------
  const float scx = 8.0f / ((gx1 - gx0) + 1e-6f);
  const float scy = 8.0f / ((gy1 - gy0) + 1e-6f);
  const float scz = 8.0f / ((gz1 - gz0) + 1e-6f);
  int key[8];
  #pragma unroll
  for (int j = 0; j < 8; ++j) {
    int cx = min(7, max(0, (int)((ox[j] - gx0) * scx)));
    int cy = min(7, max(0, (int)((oy[j] - gy0) * scy)));
    int cz = min(7, max(0, (int)((oz[j] - gz0) * scz)));
    key[j] = mort3(cx, cy, cz);
    atomicAdd(&hist[key[j]], 1);
  }
  __syncthreads();
  // ---- inclusive scan (Hillis-Steele) -> exclusive cursor ------------------
  const int hv = hist[t];
  sA[t] = hv;
  __syncthreads();
  for (int off = 1; off < 512; off <<= 1) {
    const int o = (t >= off) ? sA[t - off] : 0;
    __syncthreads();
    sA[t] += o;
    __syncthreads();
  }
  sB[t] = sA[t] - hv;                    // exclusive base == scatter cursor
  __syncthreads();
  #pragma unroll
  for (int j = 0; j < 8; ++j) {
    const int slot = atomicAdd(&sB[key[j]], 1);
    sidx[slot] = t*8 + j;
  }
  __syncthreads();
  // ---- re-own: 8 spatially coherent points + group bbox --------------------
  float px[8], py[8], pz[8], mind[8];
  int lo8[8];
  float bxn = 1e30f, bxx = -1e30f, byn = 1e30f, byy = -1e30f, bzn = 1e30f, bzz = -1e30f;
  #pragma unroll
  for (int j = 0; j < 8; ++j) {
    const int sid = sidx[t*8 + j];
    px[j] = lx[sid]; py[j] = ly[sid]; pz[j] = lz[sid];
    lo8[j] = 4095 - sid;                 // larger lo == smaller idx
    bxn = fminf(bxn, px[j]); bxx = fmaxf(bxx, px[j]);
    byn = fminf(byn, py[j]); byy = fmaxf(byy, py[j]);
    bzn = fminf(bzn, pz[j]); bzz = fmaxf(bzz, pz[j]);
  }
  const float x0 = lx[0], y0 = ly[0], z0 = lz[0];
  if (t == 0) csel[0] = 0;

  // ---- initial distances to point 0 + per-thread best key ------------------
  double bk;
  {
    double k4[4];
    #pragma unroll
    for (int jp = 0; jp < 4; ++jp) {
      const int j0 = 2*jp, j1 = 2*jp + 1;
      float dx0 = px[j0]-x0, dy0 = py[j0]-y0, dz0 = pz[j0]-z0;
      float dx1 = px[j1]-x0, dy1 = py[j1]-y0, dz1 = pz[j1]-z0;
      float d0 = (dx0*dx0 + dy0*dy0) + dz0*dz0;   // no-FMA: matches numpy
      float d1 = (dx1*dx1 + dy1*dy1) + dz1*dz1;
      mind[j0] = d0; mind[j1] = d1;
      k4[jp] = dmax(pk(d0, lo8[j0]), pk(d1, lo8[j1]));
    }
    bk = dmax(dmax(k4[0], k4[1]), dmax(k4[2], k4[3]));
  }

  for (int s = 1; s < MPC; ++s) {
    double w = rowmax16(bk);
    const int ph = (s & 1) * 32;
    if (writer) cand[ph + entry] = w;
    __syncthreads();                     // the ONLY barrier per step
    double2 pr = ((const double2*)(cand + ph))[t & 15];
    double w2 = rowmax16(dmax(pr.x, pr.y));
    const int sel = 4095 - pk_lo(w2);
    const float sx = lx[sel], sy = ly[sel], sz = lz[sel];  // broadcast reads
    if (t == 0) csel[s] = sel;
    // ---- bbox prune: skip iff PROVEN min_j d(sel,pj) >= max_j mind[j] ------
    const float bkhi = __int_as_float(__double2hiint(bk));  // = max_j mind[j]
    const float cxd = fmaxf(fmaxf(bxn - sx, sx - bxx), 0.0f);
    const float cyd = fmaxf(fmaxf(byn - sy, sy - byy), 0.0f);
    const float czd = fmaxf(fmaxf(bzn - sz, sz - bzz), 0.0f);
    const float lb = 0.99f * ((cxd*cxd + cyd*cyd) + czd*czd);  // safe lower bd
    if (lb < bkhi) {
      double k4[4];
      #pragma unroll
      for (int jp = 0; jp < 4; ++jp) {
        const int j0 = 2*jp, j1 = 2*jp + 1;
        float dx0 = px[j0]-sx, dy0 = py[j0]-sy, dz0 = pz[j0]-sz;
        float dx1 = px[j1]-sx, dy1 = py[j1]-sy, dz1 = pz[j1]-sz;
        float d0 = (dx0*dx0 + dy0*dy0) + dz0*dz0;
        float d1 = (dx1*dx1 + dy1*dy1) + dz1*dz1;
        float m0 = fminf(mind[j0], d0), m1 = fminf(mind[j1], d1);
        mind[j0] = m0; mind[j1] = m1;
        k4[jp] = dmax(pk(m0, lo8[j0]), pk(m1, lo8[j1]));
      }
      bk = dmax(dmax(k4[0], k4[1]), dmax(k4[2], k4[3]));
    }
  }
  __syncthreads();
  // ---- coalesced output pass -----------------------------------------------
  for (int c = t; c < MPC; c += 512) {
    const int il = csel[c];
    const int cl = b*MPC + c;
    const float X = lx[il], Y = ly[il], Z = lz[il];
    centers[cl] = make_float4(X, Y, Z, 0.0f);
    out[OFF_SUBPOS + cl*3 + 0] = X;
    out[OFF_SUBPOS + cl*3 + 1] = Y;
    out[OFF_SUBPOS + cl*3 + 2] = Z;
    out[OFF_SUBB + cl] = (float)b;
    out[OFF_IDCL + cl] = (float)(b*NPC + il);
  }
}

// ---------------- GEMM block (512 thr): h = x@W + b, plus BN sum/sumsq ------
__device__ void gemm_block(char* smem, const float* __restrict__ x,
                           const float* __restrict__ W, const float* __restrict__ bias,
                           float* __restrict__ h, float* __restrict__ stats, int blk)
{
  float (*xT)[68]  = (float(*)[68])(smem + SM_XT);   // [k][row], padded
  float (*Wl)[128] = (float(*)[128])(smem + SM_WL);
  float* bsum = (float*)(smem + SM_BS);
  float* bsq  = (float*)(smem + SM_BQ);
  const int t = threadIdx.x;
  const int row0 = blk * 64;
  if (t < 128) { bsum[t] = 0.0f; bsq[t] = 0.0f; }
  #pragma unroll
  for (int i = 0; i < 8; ++i) {
    const int idx = t + i*512;
    xT[idx & 63][idx >> 6] = x[(size_t)row0*64 + idx];
  }
  #pragma unroll
  for (int i = 0; i < 16; ++i) {
    const int idx = t + i*512;
    ((float*)Wl)[idx] = W[idx];
  }
  __syncthreads();
  const int tx = t & 31, ty = t >> 5;   // 32x16 threads, 4 rows x 4 cols each
  float acc[4][4] = {};
  #pragma unroll 8
  for (int k = 0; k < 64; ++k) {
    const float4 a  = *(const float4*)&xT[k][ty*4];
    const float4 b0 = *(const float4*)&Wl[k][tx*4];
    const float av[4] = {a.x, a.y, a.z, a.w};
    const float bw[4] = {b0.x, b0.y, b0.z, b0.w};
    #pragma unroll
    for (int i2 = 0; i2 < 4; ++i2)
      #pragma unroll
      for (int e = 0; e < 4; ++e)
        acc[i2][e] += av[i2] * bw[e];
  }
  const int c0 = tx*4;
  float bb[4];
  #pragma unroll
  for (int e = 0; e < 4; ++e) bb[e] = bias[c0+e];
  float s4[4] = {}, q4[4] = {};
  #pragma unroll
  for (int i2 = 0; i2 < 4; ++i2) {
    float vv[4];
    #pragma unroll
    for (int e = 0; e < 4; ++e) {
      float v = acc[i2][e] + bb[e];
      vv[e] = v; s4[e] += v; q4[e] += v*v;
    }
    const int r = row0 + ty*4 + i2;
    *(float4*)&h[(size_t)r*128 + c0] = make_float4(vv[0], vv[1], vv[2], vv[3]);
  }
  #pragma unroll
  for (int e = 0; e < 4; ++e) {
    atomicAdd(&bsum[c0+e], s4[e]);
    atomicAdd(&bsq[c0+e],  q4[e]);
  }
  __syncthreads();
  if (t < 128) {
    atomicAdd(&stats[t],      bsum[t]);
    atomicAdd(&stats[128+t],  bsq[t]);
  }
}

// ---------------- fused launcher kernel -------------------------------------
__global__ __launch_bounds__(512) void fused_fps_gemm(const float* __restrict__ pos,
                                                      float4* __restrict__ centers,
                                                      float* __restrict__ out,
                                                      const float* __restrict__ x,
                                                      const float* __restrict__ W,
                                                      const float* __restrict__ bias,
                                                      float* __restrict__ h,
                                                      float* __restrict__ stats)
{
  __shared__ __align__(16) char smem[SM_SIZE];
  if (blockIdx.x < NB) fps_block(smem, pos, centers, out);
  else                 gemm_block(smem, x, W, bias, h, stats, blockIdx.x - NB);
}

// ------- kNN + BN + pool fused: 512 blocks x 512 thr, 32 centers each -------
#define KBIG __hiloint2double(0x7f7fffff, 0xffffffff)
#define CD_STRIDE 17                     // pad: kill 32-way write conflicts

// knn_pool shared overlay (bytes)
#define KP_CD    0                      // 512 lanes * 17 f64 = 69632 (overlays lp 65536)
#define KP_SCL   69632                  // 128 f
#define KP_SSH   70144                  // 128 f
#define KP_FID   70656                  // 32*16 int = 2048 -> 72704
#define KP_SIZE  72704

__global__ __launch_bounds__(512) void knn_pool(const float* __restrict__ pos,
                                                const float4* __restrict__ centers,
                                                const float* __restrict__ h,
                                                const float* __restrict__ aux,
                                                const float* __restrict__ stats,
                                                const float* __restrict__ gamma,
                                                const float* __restrict__ beta,
                                                float* __restrict__ out)
{
  #pragma clang fp contract(off)
  __shared__ __align__(16) char sm2[KP_SIZE];
  float4* lp = (float4*)(sm2);          // [4096] pos cache; reused as cd after scan
  double* cd = (double*)(sm2 + KP_CD);
  float*  scl = (float*)(sm2 + KP_SCL);
  float*  ssh = (float*)(sm2 + KP_SSH);
  int*    fid = (int*)(sm2 + KP_FID);   // [32][16]
  // XCD-affinity swizzle (bijective, 512 % 8 == 0): each XCD owns 2 whole
  // clouds -> its pool-phase h-slice (2 x 2MB) fits the XCD's 4MB L2.
  const int vblk = ((blockIdx.x & 7) << 6) | (blockIdx.x >> 3);
  const int b   = vblk >> 5;
  const int c0  = (vblk & 31) * 32;     // first local center of this block
  const int t   = threadIdx.x;
  const int q   = t & 15;               // subset 0..15
  const int cc  = t >> 4;               // center within block, 0..31
  if (t < 128) {
    const float inv = 1.0f / 65536.0f;
    const float mu  = stats[t] * inv;
    const float var = stats[128+t] * inv - mu*mu;
    const float sc  = gamma[t] * rsqrtf(var + 1e-5f);
    scl[t] = sc;
    ssh[t] = beta[t] - mu*sc;
  }
  const float* pb = pos + (size_t)b * NPC * 3;
  for (int i = t; i < NPC; i += 512)
    lp[i] = make_float4(pb[3*i], pb[3*i+1], pb[3*i+2], 0.0f);
  __syncthreads();
  const float4 C = centers[b*MPC + c0 + cc];
  double L[16];
  #pragma unroll
  for (int k = 0; k < 16; ++k) L[k] = KBIG;
  for (int jj = 0; jj < NPC/16; ++jj) {
    const int j = jj*16 + q;            // strictly increasing within lane
    const float4 p = lp[j];
    float dx = C.x - p.x, dy = C.y - p.y, dz = C.z - p.z;
    float d2 = (dx*dx + dy*dy) + dz*dz; // no-FMA
    double nk = pk(d2, j);
    if (nk < L[0]) {                    // beats current worst -> sorted insert
      #pragma unroll
      for (int k = 0; k < 15; ++k) L[k] = dmin(L[k], dmax(L[k+1], nk));
      L[15] = dmin(L[15], nk);
    }
  }
  __syncthreads();                      // pos data no longer needed
  #pragma unroll
  for (int k = 0; k < 16; ++k) cd[t*CD_STRIDE + k] = L[k];
  __syncthreads();
  // round 1: lanes q<4 merge group {q, q+4, q+8, q+12} (own list in regs)
  if (q < 4) {
    #pragma unroll
    for (int r = 1; r <= 3; ++r) {
      const double* src = cd + (cc*16 + q + 4*r)*CD_STRIDE;
      #pragma unroll
      for (int k = 0; k < 16; ++k) {
        double nk = src[k];
        if (nk < L[0]) {
          #pragma unroll
          for (int m = 0; m < 15; ++m) L[m] = dmin(L[m], dmax(L[m+1], nk));
          L[15] = dmin(L[15], nk);
        }
      }
    }
    #pragma unroll
    for (int k = 0; k < 16; ++k) cd[t*CD_STRIDE + k] = L[k];
  }
  __syncthreads();
  // round 2: lane q==0 merges the 4 group winners -> exact global top-16
  if (q == 0) {
    #pragma unroll
    for (int r = 1; r <= 3; ++r) {
      const double* src = cd + (cc*16 + r)*CD_STRIDE;
      #pragma unroll
      for (int k = 0; k < 16; ++k) {
        double nk = src[k];
        if (nk < L[0]) {
          #pragma unroll
          for (int m = 0; m < 15; ++m) L[m] = dmin(L[m], dmax(L[m+1], nk));
          L[15] = dmin(L[15], nk);
        }
      }
    }
    #pragma unroll
    for (int k = 0; k < 16; ++k) fid[cc*16 + k] = b*NPC + pk_lo(L[k]);
  }
  __syncthreads();
  // ---- pool: 8 passes, 4 clusters per pass (128 cols each) -----------------
  for (int g = 0; g < 8; ++g) {
    const int cc2 = g*4 + (t >> 7);     // 0..31
    const int col = t & 127;
    const int cl  = b*MPC + c0 + cc2;
    const float sc = scl[col], sh = ssh[col];
    float mv = 0.0f;                    // relu >= 0, so 0 == -inf here
    #pragma unroll
    for (int k = 0; k < 16; ++k) {
      const float hv = h[(size_t)fid[cc2*16 + k]*128 + col];
      mv = fmaxf(mv, fmaxf(sc*hv + sh, 0.0f));
    }
    out[OFF_XOUT + (size_t)cl*128 + col] = mv;
    if (col < 32) {
      float s = 0.0f;
      #pragma unroll
      for (int k = 0; k < 16; ++k) s += aux[(size_t)fid[cc2*16 + k]*32 + col];
      out[OFF_AUX + (size_t)cl*32 + col] = s * (1.0f/16.0f);
    }
  }
}

extern "C" void kernel_launch(void* const* d_in, const int* in_sizes, int n_in,
                              void* d_out, int out_size, void* d_ws, size_t ws_size,
                              hipStream_t stream)
{
  const float* x     = (const float*)d_in[0];
  const float* pos   = (const float*)d_in[1];
  // d_in[2] = batch (int32) — clouds are equal-size, derived analytically
  const float* aux   = (const float*)d_in[3];
  const float* W     = (const float*)d_in[4];
  const float* bias  = (const float*)d_in[5];
  const float* gamma = (const float*)d_in[6];
  const float* beta  = (const float*)d_in[7];
  float* out = (float*)d_out;
  char*  ws  = (char*)d_ws;
  if (ws_size < (size_t)WS_NEED) return;   // insufficient scratch: bail cleanly

  float*  h       = (float*)(ws + WS_H);
  float4* centers = (float4*)(ws + WS_CENTERS);
  float*  stats   = (float*)(ws + WS_STATS);

  hipMemsetAsync(stats, 0, 256*4, stream);  // BN accumulators: zero every call
  hipLaunchKernelGGL(fused_fps_gemm, dim3(NB + PTOT/64), dim3(512), 0, stream,
                     pos, centers, out, x, W, bias, h, stats);
  hipLaunchKernelGGL(knn_pool, dim3(512), dim3(512), 0, stream,
                     pos, centers, h, aux, stats, gamma, beta, out);
}